// Round 16
// baseline (39.172 us; speedup 1.0000x reference)
//
#include <hip/hip_runtime.h>
#include <stdint.h>

#define NB 4
#define NT 2048
#define NC 1024
#define NH 64
#define NM (NB*NT)

typedef unsigned short u16;
typedef unsigned int u32;
typedef __bf16 bf16_t;
typedef float f32x4 __attribute__((ext_vector_type(4)));
typedef bf16_t bf16x8 __attribute__((ext_vector_type(8)));
typedef u16 u16x8 __attribute__((ext_vector_type(8)));
typedef u16 u16x4 __attribute__((ext_vector_type(4)));

__device__ __forceinline__ u16 f2b(float f) {
  return __builtin_bit_cast(u16, (bf16_t)f);
}

// async global->LDS 16B: LDS dest = WAVE-UNIFORM base + lane*16 (m104);
// per-lane swizzle folded into the GLOBAL source address (m173).
__device__ __forceinline__ void gl16(const void* g, void* l) {
  __builtin_amdgcn_global_load_lds(
      (const __attribute__((address_space(1))) u32*)g,
      (__attribute__((address_space(3))) u32*)l, 16, 0, 0);
}

// ---------------- Wq/Wk/Wv [1024][64] f32 -> WT [3][64][1024] bf16 (transposed)
__global__ __launch_bounds__(256) void wt_kernel(const float* __restrict__ Wq,
                                                 const float* __restrict__ Wk,
                                                 const float* __restrict__ Wv,
                                                 u16* __restrict__ wt) {
  __shared__ float t[64][65];
  const int m = blockIdx.x >> 4;
  const int kt = blockIdx.x & 15;
  const int k0 = kt * 64;
  const float* W = (m == 0) ? Wq : (m == 1) ? Wk : Wv;
  {
    const int r = threadIdx.x >> 2, c4 = threadIdx.x & 3;
    #pragma unroll
    for (int j = 0; j < 4; ++j) {
      const float4 f = *(const float4*)(W + (size_t)(k0 + r) * NH + c4 * 16 + j * 4);
      t[r][c4 * 16 + j * 4 + 0] = f.x;
      t[r][c4 * 16 + j * 4 + 1] = f.y;
      t[r][c4 * 16 + j * 4 + 2] = f.z;
      t[r][c4 * 16 + j * 4 + 3] = f.w;
    }
  }
  __syncthreads();
  const int n = threadIdx.x >> 2, kc = threadIdx.x & 3;
  u16x8 a, b;
  #pragma unroll
  for (int j = 0; j < 8; ++j) a[j] = f2b(t[kc * 16 + j][n]);
  #pragma unroll
  for (int j = 0; j < 8; ++j) b[j] = f2b(t[kc * 16 + 8 + j][n]);
  u16* dst = wt + ((size_t)(m * 64 + n)) * NC + k0 + kc * 16;
  *(u16x8*)dst = a;
  *(u16x8*)(dst + 8) = b;
}

// ---------------- proj-v4: BM=32, all 192 cols, 512 thr (8 waves = 2 row-sub x 4 col-grp).
// Traffic 229 -> 133 MB (B-panel amortized over 2x rows) — the r15 analysis showed
// staging is per-CU delivery-bound (~48 GB/s/CU), so traffic is the only lever.
__global__ __launch_bounds__(512) void proj_kernel(const float* __restrict__ x,
                                                   const u16* __restrict__ wt,
                                                   u16* __restrict__ qo,
                                                   u16* __restrict__ ko,
                                                   u16* __restrict__ vto) {
  __shared__ float fA[2][32 * 64];   // 8KB each
  __shared__ u16 sB[2][192 * 64];    // 24KB each
  const int tid = threadIdx.x;       // 0..511
  const int lane = tid & 63;
  const int wv = tid >> 6;           // 0..7
  const int wr = wv & 1;             // row subtile
  const int wh = wv >> 1;            // col group 0..3
  const int g = lane >> 4;
  const int li = lane & 15;
  const int row0 = blockIdx.x * 32;
  const int wbase = tid & 0x1C0;     // wv*64, wave-uniform

  const f32x4 zero = {0.f, 0.f, 0.f, 0.f};
  f32x4 acc[3];
  #pragma unroll
  for (int i = 0; i < 3; ++i) acc[i] = zero;

  const int ar = tid >> 4;           // A row 0..31
  const int ac = tid & 15;           // A 16B chunk 0..15
  const float* asrc0 = x + (size_t)(row0 + ar) * NC + ((ac ^ (ar & 7)) * 4);

  auto stage = [&](int kt, int nxt) {
    const int k0 = kt * 64;
    gl16(asrc0 + k0, (char*)fA[nxt] + wbase * 16);
    #pragma unroll
    for (int j = 0; j < 3; ++j) {
      const int cid = j * 512 + tid;
      const int n = cid >> 3, c = cid & 7;
      gl16(wt + (size_t)n * NC + k0 + ((c ^ (n & 7)) * 8),
           (char*)sB[nxt] + (j * 512 + wbase) * 16);
    }
  };

  stage(0, 0);
  __syncthreads();

  for (int kt = 0; kt < 16; ++kt) {
    const int cur = kt & 1;
    if (kt < 15) stage(kt + 1, cur ^ 1);
    const int arow = wr * 16 + li;
    #pragma unroll
    for (int ks = 0; ks < 2; ++ks) {
      const int c0 = ks * 8 + g * 2;
      const f32x4 a0 = *(const f32x4*)&fA[cur][arow * 64 + ((c0 ^ (arow & 7)) * 4)];
      const f32x4 a1 = *(const f32x4*)&fA[cur][arow * 64 + (((c0 + 1) ^ (arow & 7)) * 4)];
      bf16x8 a;
      a[0]=(bf16_t)a0.x; a[1]=(bf16_t)a0.y; a[2]=(bf16_t)a0.z; a[3]=(bf16_t)a0.w;
      a[4]=(bf16_t)a1.x; a[5]=(bf16_t)a1.y; a[6]=(bf16_t)a1.z; a[7]=(bf16_t)a1.w;
      #pragma unroll
      for (int f = 0; f < 3; ++f) {
        const int n = (wh * 3 + f) * 16 + li;
        const bf16x8 b = *(const bf16x8*)&sB[cur][n * 64 + (((ks * 4 + g) ^ (n & 7)) * 8)];
        acc[f] = __builtin_amdgcn_mfma_f32_16x16x32_bf16(a, b, acc[f], 0, 0, 0);
      }
    }
    __syncthreads();
  }

  // epilogue: C/D layout col=lane&15, row=(lane>>4)*4+reg; vto tile-blocked
  const int rr0 = row0 + wr * 16 + g * 4;
  #pragma unroll
  for (int f = 0; f < 3; ++f) {
    const int fn = wh * 3 + f;
    if (fn < 4) {
      #pragma unroll
      for (int i = 0; i < 4; ++i)
        qo[(size_t)(rr0 + i) * NH + fn * 16 + li] = f2b(acc[f][i]);
    } else if (fn < 8) {
      #pragma unroll
      for (int i = 0; i < 4; ++i)
        ko[(size_t)(rr0 + i) * NH + (fn - 4) * 16 + li] = f2b(acc[f][i]);
    } else {
      u16x4 pv;
      #pragma unroll
      for (int i = 0; i < 4; ++i) pv[i] = f2b(acc[f][i]);
      const int hs = (fn - 8) * 16 + li;
      const int bidx = rr0 >> 11;
      const int tt = rr0 & 2047;
      const int tile = tt >> 6, off = tt & 63;
      *(u16x4*)&vto[(((size_t)(bidx * 32 + tile) * 64) + hs) * 64 + off] = pv;
    }
  }
}

// ---------------- attention (r13 — byte-identical)
struct AttnGrp {
  union {
    struct { u16 K[2][32 * 64]; u16 V[2][64 * 32]; } st;  // 16 KB
    struct { float mo[2][16][64]; float ml[2][16]; } mg;  // 8.3 KB (aliased after loop)
  } u;
};

__global__ __launch_bounds__(512) void attn_kernel(const u16* __restrict__ qg,
                                                   const u16* __restrict__ kg,
                                                   const u16* __restrict__ vtg,
                                                   float* __restrict__ out) {
  __shared__ AttnGrp grp[8];          // 128 KB
  __shared__ u16 sP[8][16 * 32];      // 8 KB per-wave P tiles
  const int tid = threadIdx.x;
  const int lane = tid & 63;
  const int s = tid >> 3 >> 3;        // wave = kv split 0..7
  const int g = lane >> 4;
  const int li = lane & 15;
  const int jA = blockIdx.x & 63;
  const int bb = blockIdx.x >> 6;
  const int jB = 127 - jA;
  const size_t bt0 = (size_t)bb * NT;
  const int q0A = jA * 16, q0B = jB * 16;
  const int n1 = (jA >> 1) + 1;       // kv tiles (32-wide) for tile A; A+B = 65 always

  bf16x8 aqA[2], aqB[2];
  #pragma unroll
  for (int ks = 0; ks < 2; ++ks) {
    aqA[ks] = *(const bf16x8*)(qg + (bt0 + q0A + li) * NH + ks * 32 + g * 8);
    aqB[ks] = *(const bf16x8*)(qg + (bt0 + q0B + li) * NH + ks * 32 + g * 8);
  }

  const f32x4 zero = {0.f, 0.f, 0.f, 0.f};
  f32x4 oA[4], oB[4];
  float lA[4], lB[4];
  #pragma unroll
  for (int i = 0; i < 4; ++i) { oA[i] = zero; oB[i] = zero; lA[i] = 0.f; lB[i] = 0.f; }

  auto stage = [&](int v, int b) {
    const int kvt = (v < n1) ? v : v - n1;
    const size_t kbase = bt0 + (size_t)kvt * 32;
    #pragma unroll
    for (int jj = 0; jj < 4; ++jj) {
      const int idx = jj * 64 + lane;
      const int n = idx >> 3, c = idx & 7;
      gl16(kg + (kbase + n) * NH + ((c ^ (n & 7)) * 8),
           (char*)grp[s].u.st.K[b] + jj * 1024);
    }
    const size_t vbase = ((size_t)(bb * 32 + (kvt >> 1))) * 64;
    const int hoff = (kvt & 1) * 32;
    #pragma unroll
    for (int jj = 0; jj < 4; ++jj) {
      const int idx = jj * 64 + lane;
      const int n = idx >> 2, c = idx & 3;
      gl16(vtg + (vbase + n) * 64 + hoff + ((c ^ (n & 3) ^ ((n >> 2) & 3)) * 8),
           (char*)grp[s].u.st.V[b] + jj * 1024);
    }
  };

  auto computeT = [&](const bf16x8 (&aq)[2], f32x4 (&o)[4], float (&ls)[4],
                      int q0, int kv0, int b) {
    f32x4 sc2[2] = {zero, zero};
    #pragma unroll
    for (int ks = 0; ks < 2; ++ks) {
      #pragma unroll
      for (int fn = 0; fn < 2; ++fn) {
        const int n = fn * 16 + li;
        const bf16x8 bk = *(const bf16x8*)&grp[s].u.st.K[b][n * 64 + (((ks * 4 + g) ^ (n & 7)) * 8)];
        sc2[fn] = __builtin_amdgcn_mfma_f32_16x16x32_bf16(aq[ks], bk, sc2[fn], 0, 0, 0);
      }
    }
    const bool needmask = (kv0 + 31 > q0);
    #pragma unroll
    for (int fn = 0; fn < 2; ++fn) {
      #pragma unroll
      for (int i = 0; i < 4; ++i) {
        const int q = g * 4 + i;
        float v = sc2[fn][i] * 0.125f;
        if (needmask && (kv0 + fn * 16 + li > q0 + q)) v = -1e30f;
        const float e = __expf(v);
        ls[i] += e;
        const int kc = fn * 2 + (li >> 3);
        sP[s][q * 32 + ((kc ^ (q & 3) ^ ((q >> 2) & 3)) * 8) + (li & 7)] = f2b(e);
      }
    }
    const bf16x8 pa = *(const bf16x8*)&sP[s][li * 32 + ((g ^ (li & 3) ^ ((li >> 2) & 3)) * 8)];
    #pragma unroll
    for (int fn = 0; fn < 4; ++fn) {
      const int n = fn * 16 + li;
      const bf16x8 bv = *(const bf16x8*)&grp[s].u.st.V[b][n * 32 + ((g ^ (n & 3) ^ ((n >> 2) & 3)) * 8)];
      o[fn] = __builtin_amdgcn_mfma_f32_16x16x32_bf16(pa, bv, o[fn], 0, 0, 0);
    }
  };

  const int nt = (64 - s) / 8 + 1;    // 65 tiles: split s gets 8 or 9
  int v = s;
  stage(v, 0);
  for (int k = 0; k < nt; ++k) {
    if (k + 1 < nt) {
      stage(v + 8, (k + 1) & 1);
      asm volatile("s_waitcnt vmcnt(8)" ::: "memory");
    } else {
      asm volatile("s_waitcnt vmcnt(0)" ::: "memory");
    }
    const int b = k & 1;
    if (v < n1) computeT(aqA, oA, lA, q0A, v * 32, b);
    else        computeT(aqB, oB, lB, q0B, (v - n1) * 32, b);
    v += 8;
  }

  #pragma unroll
  for (int i = 0; i < 4; ++i) {
    float a = lA[i], c = lB[i];
    a += __shfl_xor(a, 1); c += __shfl_xor(c, 1);
    a += __shfl_xor(a, 2); c += __shfl_xor(c, 2);
    a += __shfl_xor(a, 4); c += __shfl_xor(c, 4);
    a += __shfl_xor(a, 8); c += __shfl_xor(c, 8);
    lA[i] = a; lB[i] = c;
  }

  #pragma unroll
  for (int fn = 0; fn < 4; ++fn) {
    #pragma unroll
    for (int i = 0; i < 4; ++i) {
      grp[s].u.mg.mo[0][g * 4 + i][fn * 16 + li] = oA[fn][i];
      grp[s].u.mg.mo[1][g * 4 + i][fn * 16 + li] = oB[fn][i];
    }
  }
  if (li == 0) {
    #pragma unroll
    for (int i = 0; i < 4; ++i) {
      grp[s].u.mg.ml[0][g * 4 + i] = lA[i];
      grp[s].u.mg.ml[1][g * 4 + i] = lB[i];
    }
  }
  __syncthreads();

  {
    const int base = tid * 4;
    const int tile = base >> 10;
    const int r = (base >> 6) & 15;
    const int c0 = base & 63;
    float L = 0.f;
    f32x4 acc = zero;
    #pragma unroll
    for (int s8 = 0; s8 < 8; ++s8) {
      L += grp[s8].u.mg.ml[tile][r];
      acc += *(const f32x4*)&grp[s8].u.mg.mo[tile][r][c0];
    }
    const int row = (tile ? q0B : q0A) + r;
    const float inv = 1.f / L;
    acc *= inv;
    *(f32x4*)&out[(bt0 + row) * NH + c0] = acc;
  }
}

extern "C" void kernel_launch(void* const* d_in, const int* in_sizes, int n_in,
                              void* d_out, int out_size, void* d_ws, size_t ws_size,
                              hipStream_t stream) {
  (void)in_sizes; (void)n_in; (void)out_size; (void)ws_size;
  const float* x  = (const float*)d_in[0];
  const float* Wq = (const float*)d_in[1];
  const float* Wk = (const float*)d_in[2];
  const float* Wv = (const float*)d_in[3];
  float* out = (float*)d_out;
  char* ws = (char*)d_ws;
  u16* qb  = (u16*)(ws);                    // 1 MB   : q bf16 [8192][64]
  u16* kb  = (u16*)(ws + (1u << 20));       // 1 MB   : k bf16 [8192][64]
  u16* vtb = (u16*)(ws + (2u << 20));       // 1 MB   : v^T bf16 tiled [4][32][64][64]
  u16* wtb = (u16*)(ws + (3u << 20));       // 384 KB : WT bf16 [3][64][1024]
  hipLaunchKernelGGL(wt_kernel,   dim3(48),  dim3(256), 0, stream, Wq, Wk, Wv, wtb);
  hipLaunchKernelGGL(proj_kernel, dim3(256), dim3(512), 0, stream, x, wtb, qb, kb, vtb);
  hipLaunchKernelGGL(attn_kernel, dim3(256), dim3(512), 0, stream, qb, kb, vtb, out);
}

// Round 18
// 38.547 us; speedup vs baseline: 1.0162x; 1.0162x over previous
//
#include <hip/hip_runtime.h>
#include <stdint.h>

#define NB 4
#define NT 2048
#define NC 1024
#define NH 64
#define NM (NB*NT)

typedef unsigned short u16;
typedef unsigned int u32;
typedef __bf16 bf16_t;
typedef float f32x4 __attribute__((ext_vector_type(4)));
typedef bf16_t bf16x8 __attribute__((ext_vector_type(8)));
typedef u16 u16x8 __attribute__((ext_vector_type(8)));
typedef u16 u16x4 __attribute__((ext_vector_type(4)));

__device__ __forceinline__ u16 f2b(float f) {
  return __builtin_bit_cast(u16, (bf16_t)f);
}

// async global->LDS 16B: LDS dest = WAVE-UNIFORM base + lane*16 (m104);
// per-lane swizzle folded into the GLOBAL source address (m173).
__device__ __forceinline__ void gl16(const void* g, void* l) {
  __builtin_amdgcn_global_load_lds(
      (const __attribute__((address_space(1))) u32*)g,
      (__attribute__((address_space(3))) u32*)l, 16, 0, 0);
}

// ---------------- Wq/Wk/Wv [1024][64] f32 -> WT [3][64][1024] bf16 (r13 layout)
__global__ __launch_bounds__(256) void wt_kernel(const float* __restrict__ Wq,
                                                 const float* __restrict__ Wk,
                                                 const float* __restrict__ Wv,
                                                 u16* __restrict__ wt) {
  __shared__ float t[64][65];
  const int m = blockIdx.x >> 4;
  const int kt = blockIdx.x & 15;
  const int k0 = kt * 64;
  const float* W = (m == 0) ? Wq : (m == 1) ? Wk : Wv;
  {
    const int r = threadIdx.x >> 2, c4 = threadIdx.x & 3;
    #pragma unroll
    for (int j = 0; j < 4; ++j) {
      const float4 f = *(const float4*)(W + (size_t)(k0 + r) * NH + c4 * 16 + j * 4);
      t[r][c4 * 16 + j * 4 + 0] = f.x;
      t[r][c4 * 16 + j * 4 + 1] = f.y;
      t[r][c4 * 16 + j * 4 + 2] = f.z;
      t[r][c4 * 16 + j * 4 + 3] = f.w;
    }
  }
  __syncthreads();
  const int n = threadIdx.x >> 2, kc = threadIdx.x & 3;
  u16x8 a, b;
  #pragma unroll
  for (int j = 0; j < 8; ++j) a[j] = f2b(t[kc * 16 + j][n]);
  #pragma unroll
  for (int j = 0; j < 8; ++j) b[j] = f2b(t[kc * 16 + 8 + j][n]);
  u16* dst = wt + ((size_t)(m * 64 + n)) * NC + k0 + kc * 16;
  *(u16x8*)dst = a;
  *(u16x8*)(dst + 8) = b;
}

// ---------------- fused QKV projection (r13 — known-good, byte-identical)
__global__ __launch_bounds__(256, 2) void proj_kernel(const float* __restrict__ x,
                                                      const u16* __restrict__ wt,
                                                      u16* __restrict__ qo,
                                                      u16* __restrict__ ko,
                                                      u16* __restrict__ vto) {
  __shared__ float fA[2][16 * 64];
  __shared__ u16 sB[2][192 * 64];
  const int tid = threadIdx.x;
  const int lane = tid & 63;
  const int w = tid >> 6;
  const int g = lane >> 4;
  const int li = lane & 15;
  const int row0 = blockIdx.x * 16;
  const int wbase = tid & 0xC0;

  const f32x4 zero = {0.f, 0.f, 0.f, 0.f};
  f32x4 acc[3];
  #pragma unroll
  for (int i = 0; i < 3; ++i) acc[i] = zero;

  const int ar = tid >> 4;
  const int ac = tid & 15;
  const float* asrc0 = x + (size_t)(row0 + ar) * NC + ((ac ^ (ar & 7)) * 4);

  auto stage = [&](int kt, int nxt) {
    const int k0 = kt * 64;
    gl16(asrc0 + k0, (char*)fA[nxt] + wbase * 16);
    #pragma unroll
    for (int j = 0; j < 6; ++j) {
      const int cid = j * 256 + tid;
      const int n = cid >> 3, c = cid & 7;
      gl16(wt + (size_t)n * NC + k0 + ((c ^ (n & 7)) * 8),
           (char*)sB[nxt] + (j * 256 + wbase) * 16);
    }
  };

  stage(0, 0);
  __syncthreads();

  for (int kt = 0; kt < 16; ++kt) {
    const int cur = kt & 1;
    if (kt < 15) stage(kt + 1, cur ^ 1);
    #pragma unroll
    for (int ks = 0; ks < 2; ++ks) {
      const int c0 = ks * 8 + g * 2;
      const f32x4 a0 = *(const f32x4*)&fA[cur][li * 64 + ((c0 ^ (li & 7)) * 4)];
      const f32x4 a1 = *(const f32x4*)&fA[cur][li * 64 + (((c0 + 1) ^ (li & 7)) * 4)];
      bf16x8 a;
      a[0]=(bf16_t)a0.x; a[1]=(bf16_t)a0.y; a[2]=(bf16_t)a0.z; a[3]=(bf16_t)a0.w;
      a[4]=(bf16_t)a1.x; a[5]=(bf16_t)a1.y; a[6]=(bf16_t)a1.z; a[7]=(bf16_t)a1.w;
      #pragma unroll
      for (int f = 0; f < 3; ++f) {
        const int n = (w * 3 + f) * 16 + li;
        const bf16x8 b = *(const bf16x8*)&sB[cur][n * 64 + (((ks * 4 + g) ^ (n & 7)) * 8)];
        acc[f] = __builtin_amdgcn_mfma_f32_16x16x32_bf16(a, b, acc[f], 0, 0, 0);
      }
    }
    __syncthreads();
  }

  const int rr0 = row0 + g * 4;
  #pragma unroll
  for (int f = 0; f < 3; ++f) {
    const int fn = w * 3 + f;
    if (fn < 4) {
      #pragma unroll
      for (int i = 0; i < 4; ++i)
        qo[(size_t)(rr0 + i) * NH + fn * 16 + li] = f2b(acc[f][i]);
    } else if (fn < 8) {
      #pragma unroll
      for (int i = 0; i < 4; ++i)
        ko[(size_t)(rr0 + i) * NH + (fn - 4) * 16 + li] = f2b(acc[f][i]);
    } else {
      u16x4 pv;
      #pragma unroll
      for (int i = 0; i < 4; ++i) pv[i] = f2b(acc[f][i]);
      const int hs = (fn - 8) * 16 + li;
      const int bidx = rr0 >> 11;
      const int tt = rr0 & 2047;
      const int tile = tt >> 6, off = tt & 63;
      *(u16x4*)&vto[(((size_t)(bidx * 32 + tile) * 64) + hs) * 64 + off] = pv;
    }
  }
}

// ---------------- attention v3: shared-KV pairs + register-V.
// Pair (jA, jB=127-jA): A's kv range is a SUBSET of B's (n1 + nB = 65, nB = 64-jA/2).
// Stage the union ONCE (K only, via gl16, wave-private dbuf, counted vmcnt);
// V comes as 4 plain vector loads/tile (different HW path than the ~45GB/s/CU
// gl16 wall). Compute B always, A piggybacks when t < n1. In-block exact merge.
struct AttnGrp {
  union {
    u16 K[2][32 * 64];                                    // 8 KB
    struct { float mo[2][16][64]; float ml[2][16]; } mg;  // merge alias
  } u;
};

__global__ __launch_bounds__(512) void attn_kernel(const u16* __restrict__ qg,
                                                   const u16* __restrict__ kg,
                                                   const u16* __restrict__ vtg,
                                                   float* __restrict__ out) {
  __shared__ AttnGrp grp[8];          // ~66 KB
  __shared__ u16 sP[8][16 * 32];      // 8 KB per-wave P tiles
  const int tid = threadIdx.x;
  const int lane = tid & 63;
  const int s = tid >> 6;             // wave 0..7 = kv-split
  const int g = lane >> 4;
  const int li = lane & 15;
  const int jA = blockIdx.x & 63;
  const int bb = blockIdx.x >> 6;
  const int jB = 127 - jA;
  const size_t bt0 = (size_t)bb * NT;
  const int q0A = jA * 16, q0B = jB * 16;
  const int n1 = (jA >> 1) + 1;       // A's kv-tile count (32-wide)
  const int nB = 64 - (jA >> 1);      // B's kv-tile count = union size

  bf16x8 aqA[2], aqB[2];
  #pragma unroll
  for (int ks = 0; ks < 2; ++ks) {
    aqA[ks] = *(const bf16x8*)(qg + (bt0 + q0A + li) * NH + ks * 32 + g * 8);
    aqB[ks] = *(const bf16x8*)(qg + (bt0 + q0B + li) * NH + ks * 32 + g * 8);
  }

  const f32x4 zero = {0.f, 0.f, 0.f, 0.f};
  f32x4 oA[4], oB[4];
  float lA[4], lB[4];
  #pragma unroll
  for (int i = 0; i < 4; ++i) { oA[i] = zero; oB[i] = zero; lA[i] = 0.f; lB[i] = 0.f; }

  // stage K tile t (32 rows x 64 hs) into wave-private buf b: exactly 4 gl16
  auto stageK = [&](int t, int b) {
    const size_t kbase = bt0 + (size_t)t * 32;
    #pragma unroll
    for (int jj = 0; jj < 4; ++jj) {
      const int idx = jj * 64 + lane;
      const int n = idx >> 3, c = idx & 7;
      gl16(kg + (kbase + n) * NH + ((c ^ (n & 7)) * 8),
           (char*)grp[s].u.K[b] + jj * 1024);
    }
  };

  auto computeT = [&](const bf16x8 (&aq)[2], f32x4 (&o)[4], float (&ls)[4],
                      int q0, int kv0, int b, const bf16x8 (&vf)[4]) {
    // QK^T: S[16q][32kv]
    f32x4 sc2[2] = {zero, zero};
    #pragma unroll
    for (int ks = 0; ks < 2; ++ks) {
      #pragma unroll
      for (int fn = 0; fn < 2; ++fn) {
        const int n = fn * 16 + li;
        const bf16x8 bk = *(const bf16x8*)&grp[s].u.K[b][n * 64 + (((ks * 4 + g) ^ (n & 7)) * 8)];
        sc2[fn] = __builtin_amdgcn_mfma_f32_16x16x32_bf16(aq[ks], bk, sc2[fn], 0, 0, 0);
      }
    }
    // static softmax: P = exp(s/8); masked -> 0
    const bool needmask = (kv0 + 31 > q0);
    #pragma unroll
    for (int fn = 0; fn < 2; ++fn) {
      #pragma unroll
      for (int i = 0; i < 4; ++i) {
        const int q = g * 4 + i;
        float v = sc2[fn][i] * 0.125f;
        if (needmask && (kv0 + fn * 16 + li > q0 + q)) v = -1e30f;
        const float e = __expf(v);
        ls[i] += e;
        const int kc = fn * 2 + (li >> 3);
        sP[s][q * 32 + ((kc ^ (q & 3) ^ ((q >> 2) & 3)) * 8) + (li & 7)] = f2b(e);
      }
    }
    // PV: o[16q][64hs] += P[16q][32kv] * V[32kv][64hs], V from registers
    const bf16x8 pa = *(const bf16x8*)&sP[s][li * 32 + ((g ^ (li & 3) ^ ((li >> 2) & 3)) * 8)];
    #pragma unroll
    for (int fn = 0; fn < 4; ++fn)
      o[fn] = __builtin_amdgcn_mfma_f32_16x16x32_bf16(pa, vf[fn], o[fn], 0, 0, 0);
  };

  stageK(s, 0);
  int k = 0;
  for (int t = s; t < nB; t += 8, ++k) {
    // V fragments for tile t: 4 plain vector loads (issued BEFORE next stage so
    // the compiler's pre-use wait keeps the gl16 prefetch in flight)
    bf16x8 vf[4];
    const size_t vrow = ((size_t)(bb * 32 + (t >> 1))) * 64;
    const int hoff = (t & 1) * 32;
    #pragma unroll
    for (int fn = 0; fn < 4; ++fn)
      vf[fn] = *(const bf16x8*)(vtg + (vrow + fn * 16 + li) * 64 + hoff + g * 8);

    if (t + 8 < nB) {
      stageK(t + 8, (k + 1) & 1);
      // outstanding (program order): gl16(t).4 | vf.4 | gl16(t+8).4 -> drain gl16(t)
      asm volatile("s_waitcnt vmcnt(8)" ::: "memory");
    } else {
      asm volatile("s_waitcnt vmcnt(4)" ::: "memory");   // drain gl16(t), keep vf
    }
    const int b = k & 1;
    computeT(aqB, oB, lB, q0B, t * 32, b, vf);
    if (t < n1) computeT(aqA, oA, lA, q0A, t * 32, b, vf);
  }

  // row-reduce l within 16-lane groups
  #pragma unroll
  for (int i = 0; i < 4; ++i) {
    float a = lA[i], c = lB[i];
    a += __shfl_xor(a, 1); c += __shfl_xor(c, 1);
    a += __shfl_xor(a, 2); c += __shfl_xor(c, 2);
    a += __shfl_xor(a, 4); c += __shfl_xor(c, 4);
    a += __shfl_xor(a, 8); c += __shfl_xor(c, 8);
    lA[i] = a; lB[i] = c;
  }

  // write partials to this wave's LDS region (wave-private alias of K bufs)
  #pragma unroll
  for (int fn = 0; fn < 4; ++fn) {
    #pragma unroll
    for (int i = 0; i < 4; ++i) {
      grp[s].u.mg.mo[0][g * 4 + i][fn * 16 + li] = oA[fn][i];
      grp[s].u.mg.mo[1][g * 4 + i][fn * 16 + li] = oB[fn][i];
    }
  }
  if (li == 0) {
    #pragma unroll
    for (int i = 0; i < 4; ++i) {
      grp[s].u.mg.ml[0][g * 4 + i] = lA[i];
      grp[s].u.mg.ml[1][g * 4 + i] = lB[i];
    }
  }
  __syncthreads();

  // combine 8 splits, write out (2048 f32 per block)
  {
    const int base = tid * 4;
    const int tile = base >> 10;
    const int r = (base >> 6) & 15;
    const int c0 = base & 63;
    float L = 0.f;
    f32x4 acc = zero;
    #pragma unroll
    for (int s8 = 0; s8 < 8; ++s8) {
      L += grp[s8].u.mg.ml[tile][r];
      acc += *(const f32x4*)&grp[s8].u.mg.mo[tile][r][c0];
    }
    const int row = (tile ? q0B : q0A) + r;
    const float inv = 1.f / L;
    acc *= inv;
    *(f32x4*)&out[(bt0 + row) * NH + c0] = acc;
  }
}

extern "C" void kernel_launch(void* const* d_in, const int* in_sizes, int n_in,
                              void* d_out, int out_size, void* d_ws, size_t ws_size,
                              hipStream_t stream) {
  (void)in_sizes; (void)n_in; (void)out_size; (void)ws_size;
  const float* x  = (const float*)d_in[0];
  const float* Wq = (const float*)d_in[1];
  const float* Wk = (const float*)d_in[2];
  const float* Wv = (const float*)d_in[3];
  float* out = (float*)d_out;
  char* ws = (char*)d_ws;
  u16* qb  = (u16*)(ws);                    // 1 MB   : q bf16 [8192][64]
  u16* kb  = (u16*)(ws + (1u << 20));       // 1 MB   : k bf16 [8192][64]
  u16* vtb = (u16*)(ws + (2u << 20));       // 1 MB   : v^T bf16 tiled [4][32][64][64]
  u16* wtb = (u16*)(ws + (3u << 20));       // 384 KB : WT bf16 [3][64][1024]
  hipLaunchKernelGGL(wt_kernel,   dim3(48),  dim3(256), 0, stream, Wq, Wk, Wv, wtb);
  hipLaunchKernelGGL(proj_kernel, dim3(512), dim3(256), 0, stream, x, wtb, qb, kb, vtb);
  hipLaunchKernelGGL(attn_kernel, dim3(256), dim3(512), 0, stream, qb, kb, vtb, out);
}